// Round 6
// baseline (81.057 us; speedup 1.0000x reference)
//
#include <hip/hip_runtime.h>

#define NC    80
#define B_    16
#define NA    3
#define HW    80
#define D_    85
#define NLAB  48
#define NCELL  (B_*NA*HW*HW)   // 307200
#define OBJBLK (NCELL/256)     // 1200
#define POSBLK (B_*108)        // 1728 (4 waves = 4 candidates each)
#define NBLK_T (OBJBLK+POSBLK) // 2928

__device__ __forceinline__ float softplusf(float x) {
    return fmaxf(x, 0.f) + log1pf(expf(-fabsf(x)));
}
__device__ __forceinline__ int clampi(int v, int lo, int hi) {
    return min(max(v, lo), hi);
}

// ---------------------------------------------------------------------------
// Fused kernel.
//   bid in [0,1200)        : obj softplus partial over 256 cells -> opart[bid]
//   bid in [1200, 2928)    : 4 waves = 4 (b,n,off) candidates -> ppart[bid-1200]
// Tail: last block (ticket) reduces all partials and writes the scalar.
// ---------------------------------------------------------------------------
__global__ __launch_bounds__(256) void k_main(const float* __restrict__ p,
                                              const float* __restrict__ lx,
                                              const int*   __restrict__ lc,
                                              float* __restrict__ opart,
                                              float* __restrict__ ppart,
                                              int*   __restrict__ cnt,
                                              float* __restrict__ out) {
    int t = threadIdx.x, bid = blockIdx.x;
    int lane = t & 63, wid = t >> 6;
    __shared__ float r4[4][5];

    if (bid < OBJBLK) {
        // ---------------- obj streaming gather ----------------
        int idx = bid * 256 + t;
        float s = softplusf(p[(size_t)idx * D_ + 4]);
        #pragma unroll
        for (int o = 32; o; o >>= 1) s += __shfl_xor(s, o);
        if (lane == 0) r4[wid][0] = s;
        __syncthreads();
        if (t == 0) opart[bid] = r4[0][0] + r4[1][0] + r4[2][0] + r4[3][0];
    } else {
        // ---------------- positive-candidate work ----------------
        int pb = bid - OBJBLK;
        int b  = pb / 108;

        __shared__ float Lgx[NLAB], Lgy[NLAB], Lgw[NLAB], Lgh[NLAB];
        __shared__ int   Lgi[NLAB], Lgj[NLAB], La[NLAB], Lc[NLAB];

        if (t < NLAB) {
            float4 L = ((const float4*)lx)[b * NLAB + t];
            float gx = L.x * 640.f, gy = L.y * 640.f;
            float gw = L.z * 640.f, gh = L.w * 640.f;
            Lgx[t] = gx; Lgy[t] = gy; Lgw[t] = gw; Lgh[t] = gh;
            Lgi[t] = (int)fminf(fmaxf(gx * 0.125f, 0.f), 79.999f);
            Lgj[t] = (int)fminf(fmaxf(gy * 0.125f, 0.f), 79.999f);
            float gtw = gw * 0.125f, gth = gh * 0.125f;
            const float aw[3] = {1.25f, 2.0f, 4.125f};
            const float ah[3] = {1.625f, 3.75f, 2.875f};
            int a = 0; float best = -1.f;
            #pragma unroll
            for (int k = 0; k < 3; k++) {
                float inter = fminf(gtw, aw[k]) * fminf(gth, ah[k]);
                float uni   = gtw * gth + aw[k] * ah[k] - inter + 1e-9f;
                float r = inter / uni;
                if (r > best) { best = r; a = k; }
            }
            La[t] = a;
            Lc[t] = lc[b * NLAB + t];
        }
        __syncthreads();

        int cand = (pb % 108) * 4 + wid;          // [0, 432)
        int n = cand / 9, off = cand % 9;
        int gi = Lgi[n], gj = Lgj[n], a = La[n];
        int ii = clampi(gi + off / 3 - 1, 0, 79);
        int jj = clampi(gj + off % 3 - 1, 0, 79);

        bool viol = false;
        if (lane < 9) {
            if (lane < off) {
                int i2 = clampi(gi + lane / 3 - 1, 0, 79);
                int j2 = clampi(gj + lane % 3 - 1, 0, 79);
                viol = (i2 == ii) && (j2 == jj);
            }
        } else {
            int n2 = n + 1 + (lane - 9);
            if (n2 < NLAB && La[n2] == a) {
                int g2 = Lgi[n2], h2 = Lgj[n2];
                viol = ii >= max(g2 - 1, 0) && ii <= min(g2 + 1, 79) &&
                       jj >= max(h2 - 1, 0) && jj <= min(h2 + 1, 79);
            }
        }
        bool own = (__ballot(viol) == 0ull);

        float box = 0.f, cls = 0.f, xc = 0.f, npf = 0.f;
        if (own) {  // wave-uniform
            int cell = ((b * NA + a) * HW + jj) * HW + ii;
            const float* pc = p + (size_t)cell * D_;
            int c = Lc[n];

            float x = pc[5 + lane];
            float cs = softplusf(x) - ((lane == c) ? x : 0.f);
            if (lane < 16) {
                float x2 = pc[69 + lane];
                cs += softplusf(x2) - ((lane + 64 == c) ? x2 : 0.f);
            }
            #pragma unroll
            for (int o = 32; o; o >>= 1) cs += __shfl_xor(cs, o);

            if (lane == 0) {
                npf = 1.f;
                cls = cs;
                xc  = pc[4];

                float awv = (a == 0) ? 10.f : ((a == 1) ? 16.f : 33.f);
                float ahv = (a == 0) ? 13.f : ((a == 1) ? 30.f : 23.f);
                float p0 = pc[0], p1 = pc[1], p2 = pc[2], p3 = pc[3];
                float sx = 1.f / (1.f + expf(-p0));
                float sy = 1.f / (1.f + expf(-p1));
                float px = ((float)ii + sx) * 8.f;
                float py = ((float)jj + sy) * 8.f;
                float pw = expf(p2) * awv;
                float ph = expf(p3) * ahv;

                float gx = Lgx[n], gy = Lgy[n], gw = Lgw[n], gh = Lgh[n];

                float px1 = px - pw * 0.5f, px2 = px + pw * 0.5f;
                float py1 = py - ph * 0.5f, py2 = py + ph * 0.5f;
                float gx1 = gx - gw * 0.5f, gx2 = gx + gw * 0.5f;
                float gy1 = gy - gh * 0.5f, gy2 = gy + gh * 0.5f;

                float iw = fmaxf(fminf(px2, gx2) - fmaxf(px1, gx1), 0.f);
                float ih = fmaxf(fminf(py2, gy2) - fmaxf(py1, gy1), 0.f);
                float inter = iw * ih;
                float ap = fmaxf(px2 - px1, 0.f) * fmaxf(py2 - py1, 0.f);
                float ag = fmaxf(gx2 - gx1, 0.f) * fmaxf(gy2 - gy1, 0.f);
                float uni = ap + ag - inter + 1e-7f;
                float iou = inter / uni;

                float cw = fmaxf(fmaxf(px2, gx2) - fminf(px1, gx1), 0.f);
                float ch = fmaxf(fmaxf(py2, gy2) - fminf(py1, gy1), 0.f);
                float c2 = cw * cw + ch * ch + 1e-7f;
                float rho2 = (px - gx) * (px - gx) + (py - gy) * (py - gy);

                float dv = atanf(gw / (gh + 1e-7f)) - atanf(pw / (ph + 1e-7f));
                float v = 0.40528473456935108577f * dv * dv;   // 4/pi^2
                float alpha = v / (1.f - iou + v + 1e-7f);
                box = 1.f - (iou - rho2 / c2 - alpha * v);
            }
        }

        if (lane == 0) { r4[wid][0] = box; r4[wid][1] = cls; r4[wid][2] = xc; r4[wid][3] = npf; }
        __syncthreads();
        if (t == 0) {
            float4 o;
            o.x = r4[0][0] + r4[1][0] + r4[2][0] + r4[3][0];
            o.y = r4[0][1] + r4[1][1] + r4[2][1] + r4[3][1];
            o.z = r4[0][2] + r4[1][2] + r4[2][2] + r4[3][2];
            o.w = r4[0][3] + r4[1][3] + r4[2][3] + r4[3][3];
            ((float4*)ppart)[pb] = o;
        }
    }

    // ---------------- last-block finalize ----------------
    __shared__ bool amLast;
    __syncthreads();                 // partial store issued
    if (t == 0) {
        __threadfence();             // release partials device-wide
        amLast = (atomicAdd(cnt, 1) == NBLK_T - 1);
    }
    __syncthreads();
    if (!amLast) return;
    __threadfence();                 // acquire all partials

    float o = 0.f, box = 0.f, cls = 0.f, xc = 0.f, np = 0.f;
    #pragma unroll
    for (int k = 0; k < 5; k++) {
        int i = t + k * 256;
        if (i < OBJBLK) o += opart[i];
    }
    #pragma unroll
    for (int k = 0; k < 7; k++) {
        int i = t + k * 256;
        if (i < POSBLK) {
            float4 v = ((const float4*)ppart)[i];
            box += v.x; cls += v.y; xc += v.z; np += v.w;
        }
    }
    #pragma unroll
    for (int s = 32; s; s >>= 1) {
        o   += __shfl_xor(o,   s);
        box += __shfl_xor(box, s);
        cls += __shfl_xor(cls, s);
        xc  += __shfl_xor(xc,  s);
        np  += __shfl_xor(np,  s);
    }
    __shared__ float r[4][5];
    if (lane == 0) { r[wid][0]=o; r[wid][1]=box; r[wid][2]=cls; r[wid][3]=xc; r[wid][4]=np; }
    __syncthreads();
    if (t == 0) {
        float O  = r[0][0] + r[1][0] + r[2][0] + r[3][0];
        float Bx = r[0][1] + r[1][1] + r[2][1] + r[3][1];
        float Cl = r[0][2] + r[1][2] + r[2][2] + r[3][2];
        float Xc = r[0][3] + r[1][3] + r[2][3] + r[3][3];
        float Np = r[0][4] + r[1][4] + r[2][4] + r[3][4];
        float npos = fmaxf(Np, 1.f);
        out[0] = 7.5f * Bx / npos
               + (O - Xc) / (float)NCELL
               + 0.5f * Cl / (npos * (float)NC);
    }
}

extern "C" void kernel_launch(void* const* d_in, const int* in_sizes, int n_in,
                              void* d_out, int out_size, void* d_ws, size_t ws_size,
                              hipStream_t stream) {
    const float* p  = (const float*)d_in[0];
    const float* lx = (const float*)d_in[1];
    const int*   lc = (const int*)d_in[2];
    float*       out = (float*)d_out;

    float* opart = (float*)d_ws;                          // 1200 floats @ 0
    float* ppart = (float*)((char*)d_ws + 8192);          // 1728 float4
    int*   cnt   = (int*)((char*)d_ws + 8192 + 27648);    // 1 int

    hipMemsetAsync(cnt, 0, 4, stream);                    // ticket reset (tiny DMA node)
    k_main<<<NBLK_T, 256, 0, stream>>>(p, lx, lc, opart, ppart, cnt, out);
}

// Round 7
// 23.132 us; speedup vs baseline: 3.5041x; 3.5041x over previous
//
#include <hip/hip_runtime.h>

#define NC    80
#define B_    16
#define NA    3
#define HW    80
#define D_    85
#define NLAB  48
#define NCELL  (B_*NA*HW*HW)   // 307200
#define OBJBLK (NCELL/256)     // 1200
#define POSBLK (B_*108)        // 1728 (4 waves = 4 candidates each)
#define NBLK_T (OBJBLK+POSBLK) // 2928

__device__ __forceinline__ float softplusf(float x) {
    return fmaxf(x, 0.f) + log1pf(expf(-fabsf(x)));
}
__device__ __forceinline__ int clampi(int v, int lo, int hi) {
    return min(max(v, lo), hi);
}

// ---------------------------------------------------------------------------
// Fused main kernel (NO tail sync — partials only):
//   bid in [0,1200)     : obj softplus partial over 256 cells -> opart[bid]
//   bid in [1200,2928)  : 4 waves = 4 (b,n,off) candidates -> ppart[bid-1200]
// ---------------------------------------------------------------------------
__global__ __launch_bounds__(256) void k_main(const float* __restrict__ p,
                                              const float* __restrict__ lx,
                                              const int*   __restrict__ lc,
                                              float* __restrict__ opart,
                                              float* __restrict__ ppart) {
    int t = threadIdx.x, bid = blockIdx.x;
    int lane = t & 63, wid = t >> 6;
    __shared__ float r4[4][4];

    if (bid < OBJBLK) {
        // ---------------- obj streaming gather ----------------
        int idx = bid * 256 + t;
        float s = softplusf(p[(size_t)idx * D_ + 4]);
        #pragma unroll
        for (int o = 32; o; o >>= 1) s += __shfl_xor(s, o);
        if (lane == 0) r4[wid][0] = s;
        __syncthreads();
        if (t == 0) opart[bid] = r4[0][0] + r4[1][0] + r4[2][0] + r4[3][0];
        return;
    }

    // ---------------- positive-candidate work ----------------
    int pb = bid - OBJBLK;
    int b  = pb / 108;

    __shared__ float Lgx[NLAB], Lgy[NLAB], Lgw[NLAB], Lgh[NLAB];
    __shared__ int   Lgi[NLAB], Lgj[NLAB], La[NLAB], Lc[NLAB];

    if (t < NLAB) {
        float4 L = ((const float4*)lx)[b * NLAB + t];
        float gx = L.x * 640.f, gy = L.y * 640.f;
        float gw = L.z * 640.f, gh = L.w * 640.f;
        Lgx[t] = gx; Lgy[t] = gy; Lgw[t] = gw; Lgh[t] = gh;
        Lgi[t] = (int)fminf(fmaxf(gx * 0.125f, 0.f), 79.999f);
        Lgj[t] = (int)fminf(fmaxf(gy * 0.125f, 0.f), 79.999f);
        float gtw = gw * 0.125f, gth = gh * 0.125f;
        const float aw[3] = {1.25f, 2.0f, 4.125f};
        const float ah[3] = {1.625f, 3.75f, 2.875f};
        int a = 0; float best = -1.f;
        #pragma unroll
        for (int k = 0; k < 3; k++) {
            float inter = fminf(gtw, aw[k]) * fminf(gth, ah[k]);
            float uni   = gtw * gth + aw[k] * ah[k] - inter + 1e-9f;
            float r = inter / uni;
            if (r > best) { best = r; a = k; }
        }
        La[t] = a;
        Lc[t] = lc[b * NLAB + t];
    }
    __syncthreads();

    int cand = (pb % 108) * 4 + wid;          // [0, 432)
    int n = cand / 9, off = cand % 9;
    int gi = Lgi[n], gj = Lgj[n], a = La[n];
    int ii = clampi(gi + off / 3 - 1, 0, 79);
    int jj = clampi(gj + off % 3 - 1, 0, 79);

    // ownership: one ballot. lanes 0..8: clip-duplicate dedup; lanes 9..55:
    // later same-anchor label covering this cell overwrites us.
    bool viol = false;
    if (lane < 9) {
        if (lane < off) {
            int i2 = clampi(gi + lane / 3 - 1, 0, 79);
            int j2 = clampi(gj + lane % 3 - 1, 0, 79);
            viol = (i2 == ii) && (j2 == jj);
        }
    } else {
        int n2 = n + 1 + (lane - 9);
        if (n2 < NLAB && La[n2] == a) {
            int g2 = Lgi[n2], h2 = Lgj[n2];
            viol = ii >= max(g2 - 1, 0) && ii <= min(g2 + 1, 79) &&
                   jj >= max(h2 - 1, 0) && jj <= min(h2 + 1, 79);
        }
    }
    bool own = (__ballot(viol) == 0ull);

    float box = 0.f, cls = 0.f, xc = 0.f, npf = 0.f;
    if (own) {  // wave-uniform branch
        int cell = ((b * NA + a) * HW + jj) * HW + ii;
        const float* pc = p + (size_t)cell * D_;
        int c = Lc[n];

        float x = pc[5 + lane];
        float cs = softplusf(x) - ((lane == c) ? x : 0.f);
        if (lane < 16) {
            float x2 = pc[69 + lane];
            cs += softplusf(x2) - ((lane + 64 == c) ? x2 : 0.f);
        }
        #pragma unroll
        for (int o = 32; o; o >>= 1) cs += __shfl_xor(cs, o);

        if (lane == 0) {
            npf = 1.f;
            cls = cs;
            xc  = pc[4];

            float awv = (a == 0) ? 10.f : ((a == 1) ? 16.f : 33.f);
            float ahv = (a == 0) ? 13.f : ((a == 1) ? 30.f : 23.f);
            float p0 = pc[0], p1 = pc[1], p2 = pc[2], p3 = pc[3];
            float sx = 1.f / (1.f + expf(-p0));
            float sy = 1.f / (1.f + expf(-p1));
            float px = ((float)ii + sx) * 8.f;
            float py = ((float)jj + sy) * 8.f;
            float pw = expf(p2) * awv;
            float ph = expf(p3) * ahv;

            float gx = Lgx[n], gy = Lgy[n], gw = Lgw[n], gh = Lgh[n];

            float px1 = px - pw * 0.5f, px2 = px + pw * 0.5f;
            float py1 = py - ph * 0.5f, py2 = py + ph * 0.5f;
            float gx1 = gx - gw * 0.5f, gx2 = gx + gw * 0.5f;
            float gy1 = gy - gh * 0.5f, gy2 = gy + gh * 0.5f;

            float iw = fmaxf(fminf(px2, gx2) - fmaxf(px1, gx1), 0.f);
            float ih = fmaxf(fminf(py2, gy2) - fmaxf(py1, gy1), 0.f);
            float inter = iw * ih;
            float ap = fmaxf(px2 - px1, 0.f) * fmaxf(py2 - py1, 0.f);
            float ag = fmaxf(gx2 - gx1, 0.f) * fmaxf(gy2 - gy1, 0.f);
            float uni = ap + ag - inter + 1e-7f;
            float iou = inter / uni;

            float cw = fmaxf(fmaxf(px2, gx2) - fminf(px1, gx1), 0.f);
            float ch = fmaxf(fmaxf(py2, gy2) - fminf(py1, gy1), 0.f);
            float c2 = cw * cw + ch * ch + 1e-7f;
            float rho2 = (px - gx) * (px - gx) + (py - gy) * (py - gy);

            float dv = atanf(gw / (gh + 1e-7f)) - atanf(pw / (ph + 1e-7f));
            float v = 0.40528473456935108577f * dv * dv;   // 4/pi^2
            float alpha = v / (1.f - iou + v + 1e-7f);
            box = 1.f - (iou - rho2 / c2 - alpha * v);
        }
    }

    if (lane == 0) { r4[wid][0] = box; r4[wid][1] = cls; r4[wid][2] = xc; r4[wid][3] = npf; }
    __syncthreads();
    if (t == 0) {
        float4 o;
        o.x = r4[0][0] + r4[1][0] + r4[2][0] + r4[3][0];
        o.y = r4[0][1] + r4[1][1] + r4[2][1] + r4[3][1];
        o.z = r4[0][2] + r4[1][2] + r4[2][2] + r4[3][2];
        o.w = r4[0][3] + r4[1][3] + r4[2][3] + r4[3][3];
        ((float4*)ppart)[pb] = o;
    }
}

// ---------------------------------------------------------------------------
// k_fin: reduce 1200 obj partials + 1728 pos float4 partials, compose scalar.
// ---------------------------------------------------------------------------
__global__ __launch_bounds__(256) void k_fin(const float* __restrict__ opart,
                                             const float* __restrict__ ppart,
                                             float* __restrict__ out) {
    int t = threadIdx.x, lane = t & 63, wid = t >> 6;
    float o = 0.f, box = 0.f, cls = 0.f, xc = 0.f, np = 0.f;
    #pragma unroll
    for (int k = 0; k < 5; k++) {
        int i = t + k * 256;
        if (i < OBJBLK) o += opart[i];
    }
    #pragma unroll
    for (int k = 0; k < 7; k++) {
        int i = t + k * 256;
        if (i < POSBLK) {
            float4 v = ((const float4*)ppart)[i];
            box += v.x; cls += v.y; xc += v.z; np += v.w;
        }
    }
    #pragma unroll
    for (int s = 32; s; s >>= 1) {
        o   += __shfl_xor(o,   s);
        box += __shfl_xor(box, s);
        cls += __shfl_xor(cls, s);
        xc  += __shfl_xor(xc,  s);
        np  += __shfl_xor(np,  s);
    }
    __shared__ float r[4][5];
    if (lane == 0) { r[wid][0]=o; r[wid][1]=box; r[wid][2]=cls; r[wid][3]=xc; r[wid][4]=np; }
    __syncthreads();
    if (t == 0) {
        float O  = r[0][0] + r[1][0] + r[2][0] + r[3][0];
        float Bx = r[0][1] + r[1][1] + r[2][1] + r[3][1];
        float Cl = r[0][2] + r[1][2] + r[2][2] + r[3][2];
        float Xc = r[0][3] + r[1][3] + r[2][3] + r[3][3];
        float Np = r[0][4] + r[1][4] + r[2][4] + r[3][4];
        float npos = fmaxf(Np, 1.f);
        out[0] = 7.5f * Bx / npos
               + (O - Xc) / (float)NCELL
               + 0.5f * Cl / (npos * (float)NC);
    }
}

extern "C" void kernel_launch(void* const* d_in, const int* in_sizes, int n_in,
                              void* d_out, int out_size, void* d_ws, size_t ws_size,
                              hipStream_t stream) {
    const float* p  = (const float*)d_in[0];
    const float* lx = (const float*)d_in[1];
    const int*   lc = (const int*)d_in[2];
    float*       out = (float*)d_out;

    float* opart = (float*)d_ws;                          // 1200 floats
    float* ppart = (float*)((char*)d_ws + 8192);          // 1728 float4

    k_main<<<NBLK_T, 256, 0, stream>>>(p, lx, lc, opart, ppart);
    k_fin<<<1, 256, 0, stream>>>(opart, ppart, out);
}

// Round 8
// 21.853 us; speedup vs baseline: 3.7092x; 1.0585x over previous
//
#include <hip/hip_runtime.h>

#define NC    80
#define B_    16
#define NA    3
#define HW    80
#define D_    85
#define NLAB  48
#define NCELL  (B_*NA*HW*HW)   // 307200
#define OBJBLK 600             // 600 blocks x 256 thr x 2 cells = 307200
#define POSBLK (B_*108)        // 1728 (4 waves = 4 candidates each)
#define NBLK_T (OBJBLK+POSBLK) // 2328

__device__ __forceinline__ float softplusf(float x) {
    return fmaxf(x, 0.f) + log1pf(expf(-fabsf(x)));
}
__device__ __forceinline__ int clampi(int v, int lo, int hi) {
    return min(max(v, lo), hi);
}

// ---------------------------------------------------------------------------
// Fused main kernel (no tail sync — partials only):
//   bid in [0,600)      : obj softplus partial over 512 cells (2/thread, MLP=2)
//   bid in [600,2328)   : 4 waves = 4 (b,n,off) candidates -> ppart[bid-600]
// ---------------------------------------------------------------------------
__global__ __launch_bounds__(256) void k_main(const float* __restrict__ p,
                                              const float* __restrict__ lx,
                                              const int*   __restrict__ lc,
                                              float* __restrict__ opart,
                                              float* __restrict__ ppart) {
    int t = threadIdx.x, bid = blockIdx.x;
    int lane = t & 63, wid = t >> 6;
    __shared__ float r4[4][4];

    if (bid < OBJBLK) {
        // ---- obj gather: 2 independent strided loads per thread ----
        int base = bid * 512;
        const float* a0 = p + (size_t)(base + t) * D_ + 4;
        const float* a1 = p + (size_t)(base + 256 + t) * D_ + 4;
        float x0 = *a0;          // both loads issue before either use:
        float x1 = *a1;          // 2 lines in flight per lane
        float s = softplusf(x0) + softplusf(x1);
        #pragma unroll
        for (int o = 32; o; o >>= 1) s += __shfl_xor(s, o);
        if (lane == 0) r4[wid][0] = s;
        __syncthreads();
        if (t == 0) opart[bid] = r4[0][0] + r4[1][0] + r4[2][0] + r4[3][0];
        return;
    }

    // ---------------- positive-candidate work ----------------
    int pb = bid - OBJBLK;
    int b  = pb / 108;

    __shared__ float Lgx[NLAB], Lgy[NLAB], Lgw[NLAB], Lgh[NLAB];
    __shared__ int   Lgi[NLAB], Lgj[NLAB], La[NLAB], Lc[NLAB];

    if (t < NLAB) {
        float4 L = ((const float4*)lx)[b * NLAB + t];
        float gx = L.x * 640.f, gy = L.y * 640.f;
        float gw = L.z * 640.f, gh = L.w * 640.f;
        Lgx[t] = gx; Lgy[t] = gy; Lgw[t] = gw; Lgh[t] = gh;
        Lgi[t] = (int)fminf(fmaxf(gx * 0.125f, 0.f), 79.999f);
        Lgj[t] = (int)fminf(fmaxf(gy * 0.125f, 0.f), 79.999f);
        float gtw = gw * 0.125f, gth = gh * 0.125f;
        const float aw[3] = {1.25f, 2.0f, 4.125f};
        const float ah[3] = {1.625f, 3.75f, 2.875f};
        int a = 0; float best = -1.f;
        #pragma unroll
        for (int k = 0; k < 3; k++) {
            float inter = fminf(gtw, aw[k]) * fminf(gth, ah[k]);
            float uni   = gtw * gth + aw[k] * ah[k] - inter + 1e-9f;
            float r = inter / uni;
            if (r > best) { best = r; a = k; }
        }
        La[t] = a;
        Lc[t] = lc[b * NLAB + t];
    }
    __syncthreads();

    int cand = (pb % 108) * 4 + wid;          // [0, 432)
    int n = cand / 9, off = cand % 9;
    int gi = Lgi[n], gj = Lgj[n], a = La[n];
    int ii = clampi(gi + off / 3 - 1, 0, 79);
    int jj = clampi(gj + off % 3 - 1, 0, 79);

    // ownership: one ballot. lanes 0..8: clip-duplicate dedup; lanes 9..55:
    // later same-anchor label covering this cell overwrites us.
    bool viol = false;
    if (lane < 9) {
        if (lane < off) {
            int i2 = clampi(gi + lane / 3 - 1, 0, 79);
            int j2 = clampi(gj + lane % 3 - 1, 0, 79);
            viol = (i2 == ii) && (j2 == jj);
        }
    } else {
        int n2 = n + 1 + (lane - 9);
        if (n2 < NLAB && La[n2] == a) {
            int g2 = Lgi[n2], h2 = Lgj[n2];
            viol = ii >= max(g2 - 1, 0) && ii <= min(g2 + 1, 79) &&
                   jj >= max(h2 - 1, 0) && jj <= min(h2 + 1, 79);
        }
    }
    bool own = (__ballot(viol) == 0ull);

    float box = 0.f, cls = 0.f, xc = 0.f, npf = 0.f;
    if (own) {  // wave-uniform branch
        int cell = ((b * NA + a) * HW + jj) * HW + ii;
        const float* pc = p + (size_t)cell * D_;
        int c = Lc[n];

        float x = pc[5 + lane];
        float cs = softplusf(x) - ((lane == c) ? x : 0.f);
        if (lane < 16) {
            float x2 = pc[69 + lane];
            cs += softplusf(x2) - ((lane + 64 == c) ? x2 : 0.f);
        }
        #pragma unroll
        for (int o = 32; o; o >>= 1) cs += __shfl_xor(cs, o);

        if (lane == 0) {
            npf = 1.f;
            cls = cs;
            xc  = pc[4];

            float awv = (a == 0) ? 10.f : ((a == 1) ? 16.f : 33.f);
            float ahv = (a == 0) ? 13.f : ((a == 1) ? 30.f : 23.f);
            float p0 = pc[0], p1 = pc[1], p2 = pc[2], p3 = pc[3];
            float sx = 1.f / (1.f + expf(-p0));
            float sy = 1.f / (1.f + expf(-p1));
            float px = ((float)ii + sx) * 8.f;
            float py = ((float)jj + sy) * 8.f;
            float pw = expf(p2) * awv;
            float ph = expf(p3) * ahv;

            float gx = Lgx[n], gy = Lgy[n], gw = Lgw[n], gh = Lgh[n];

            float px1 = px - pw * 0.5f, px2 = px + pw * 0.5f;
            float py1 = py - ph * 0.5f, py2 = py + ph * 0.5f;
            float gx1 = gx - gw * 0.5f, gx2 = gx + gw * 0.5f;
            float gy1 = gy - gh * 0.5f, gy2 = gy + gh * 0.5f;

            float iw = fmaxf(fminf(px2, gx2) - fmaxf(px1, gx1), 0.f);
            float ih = fmaxf(fminf(py2, gy2) - fmaxf(py1, gy1), 0.f);
            float inter = iw * ih;
            float ap = fmaxf(px2 - px1, 0.f) * fmaxf(py2 - py1, 0.f);
            float ag = fmaxf(gx2 - gx1, 0.f) * fmaxf(gy2 - gy1, 0.f);
            float uni = ap + ag - inter + 1e-7f;
            float iou = inter / uni;

            float cw = fmaxf(fmaxf(px2, gx2) - fminf(px1, gx1), 0.f);
            float ch = fmaxf(fmaxf(py2, gy2) - fminf(py1, gy1), 0.f);
            float c2 = cw * cw + ch * ch + 1e-7f;
            float rho2 = (px - gx) * (px - gx) + (py - gy) * (py - gy);

            float dv = atanf(gw / (gh + 1e-7f)) - atanf(pw / (ph + 1e-7f));
            float v = 0.40528473456935108577f * dv * dv;   // 4/pi^2
            float alpha = v / (1.f - iou + v + 1e-7f);
            box = 1.f - (iou - rho2 / c2 - alpha * v);
        }
    }

    if (lane == 0) { r4[wid][0] = box; r4[wid][1] = cls; r4[wid][2] = xc; r4[wid][3] = npf; }
    __syncthreads();
    if (t == 0) {
        float4 o;
        o.x = r4[0][0] + r4[1][0] + r4[2][0] + r4[3][0];
        o.y = r4[0][1] + r4[1][1] + r4[2][1] + r4[3][1];
        o.z = r4[0][2] + r4[1][2] + r4[2][2] + r4[3][2];
        o.w = r4[0][3] + r4[1][3] + r4[2][3] + r4[3][3];
        ((float4*)ppart)[pb] = o;
    }
}

// ---------------------------------------------------------------------------
// k_fin: reduce 600 obj partials + 1728 pos float4 partials, compose scalar.
// ---------------------------------------------------------------------------
__global__ __launch_bounds__(256) void k_fin(const float* __restrict__ opart,
                                             const float* __restrict__ ppart,
                                             float* __restrict__ out) {
    int t = threadIdx.x, lane = t & 63, wid = t >> 6;
    float o = 0.f, box = 0.f, cls = 0.f, xc = 0.f, np = 0.f;
    #pragma unroll
    for (int k = 0; k < 3; k++) {
        int i = t + k * 256;
        if (i < OBJBLK) o += opart[i];
    }
    #pragma unroll
    for (int k = 0; k < 7; k++) {
        int i = t + k * 256;
        if (i < POSBLK) {
            float4 v = ((const float4*)ppart)[i];
            box += v.x; cls += v.y; xc += v.z; np += v.w;
        }
    }
    #pragma unroll
    for (int s = 32; s; s >>= 1) {
        o   += __shfl_xor(o,   s);
        box += __shfl_xor(box, s);
        cls += __shfl_xor(cls, s);
        xc  += __shfl_xor(xc,  s);
        np  += __shfl_xor(np,  s);
    }
    __shared__ float r[4][5];
    if (lane == 0) { r[wid][0]=o; r[wid][1]=box; r[wid][2]=cls; r[wid][3]=xc; r[wid][4]=np; }
    __syncthreads();
    if (t == 0) {
        float O  = r[0][0] + r[1][0] + r[2][0] + r[3][0];
        float Bx = r[0][1] + r[1][1] + r[2][1] + r[3][1];
        float Cl = r[0][2] + r[1][2] + r[2][2] + r[3][2];
        float Xc = r[0][3] + r[1][3] + r[2][3] + r[3][3];
        float Np = r[0][4] + r[1][4] + r[2][4] + r[3][4];
        float npos = fmaxf(Np, 1.f);
        out[0] = 7.5f * Bx / npos
               + (O - Xc) / (float)NCELL
               + 0.5f * Cl / (npos * (float)NC);
    }
}

extern "C" void kernel_launch(void* const* d_in, const int* in_sizes, int n_in,
                              void* d_out, int out_size, void* d_ws, size_t ws_size,
                              hipStream_t stream) {
    const float* p  = (const float*)d_in[0];
    const float* lx = (const float*)d_in[1];
    const int*   lc = (const int*)d_in[2];
    float*       out = (float*)d_out;

    float* opart = (float*)d_ws;                          // 600 floats
    float* ppart = (float*)((char*)d_ws + 8192);          // 1728 float4

    k_main<<<NBLK_T, 256, 0, stream>>>(p, lx, lc, opart, ppart);
    k_fin<<<1, 256, 0, stream>>>(opart, ppart, out);
}

// Round 9
// 21.399 us; speedup vs baseline: 3.7878x; 1.0212x over previous
//
#include <hip/hip_runtime.h>

#define NC    80
#define B_    16
#define NA    3
#define HW    80
#define D_    85
#define NLAB  48
#define NCELL  (B_*NA*HW*HW)   // 307200
#define OBJBLK 300             // 300 blocks x 256 thr x 4 cells = 307200
#define POSBLK (B_*108)        // 1728 (4 waves = 4 candidates each)
#define NBLK_T (OBJBLK+POSBLK) // 2028  (~residency capacity: 2048 blocks)

__device__ __forceinline__ float softplusf(float x) {
    return fmaxf(x, 0.f) + log1pf(expf(-fabsf(x)));
}
__device__ __forceinline__ int clampi(int v, int lo, int hi) {
    return min(max(v, lo), hi);
}

// ---------------------------------------------------------------------------
// Fused main kernel (no tail sync — partials only):
//   bid in [0,300)      : obj softplus partial over 1024 cells (4/thread, MLP=4)
//   bid in [300,2028)   : 4 waves = 4 (b,n,off) candidates -> ppart[bid-300]
// ---------------------------------------------------------------------------
__global__ __launch_bounds__(256) void k_main(const float* __restrict__ p,
                                              const float* __restrict__ lx,
                                              const int*   __restrict__ lc,
                                              float* __restrict__ opart,
                                              float* __restrict__ ppart) {
    int t = threadIdx.x, bid = blockIdx.x;
    int lane = t & 63, wid = t >> 6;
    __shared__ float r4[4][4];

    if (bid < OBJBLK) {
        // ---- obj gather: 4 independent strided loads, all in flight ----
        int base = bid * 1024;
        const float* a0 = p + (size_t)(base + t      ) * D_ + 4;
        const float* a1 = p + (size_t)(base + t + 256) * D_ + 4;
        const float* a2 = p + (size_t)(base + t + 512) * D_ + 4;
        const float* a3 = p + (size_t)(base + t + 768) * D_ + 4;
        float x0 = *a0;
        float x1 = *a1;
        float x2 = *a2;
        float x3 = *a3;
        float s = (softplusf(x0) + softplusf(x1)) + (softplusf(x2) + softplusf(x3));
        #pragma unroll
        for (int o = 32; o; o >>= 1) s += __shfl_xor(s, o);
        if (lane == 0) r4[wid][0] = s;
        __syncthreads();
        if (t == 0) opart[bid] = r4[0][0] + r4[1][0] + r4[2][0] + r4[3][0];
        return;
    }

    // ---------------- positive-candidate work ----------------
    int pb = bid - OBJBLK;
    int b  = pb / 108;

    __shared__ float Lgx[NLAB], Lgy[NLAB], Lgw[NLAB], Lgh[NLAB];
    __shared__ int   Lgi[NLAB], Lgj[NLAB], La[NLAB], Lc[NLAB];

    if (t < NLAB) {
        float4 L = ((const float4*)lx)[b * NLAB + t];
        float gx = L.x * 640.f, gy = L.y * 640.f;
        float gw = L.z * 640.f, gh = L.w * 640.f;
        Lgx[t] = gx; Lgy[t] = gy; Lgw[t] = gw; Lgh[t] = gh;
        Lgi[t] = (int)fminf(fmaxf(gx * 0.125f, 0.f), 79.999f);
        Lgj[t] = (int)fminf(fmaxf(gy * 0.125f, 0.f), 79.999f);
        float gtw = gw * 0.125f, gth = gh * 0.125f;
        const float aw[3] = {1.25f, 2.0f, 4.125f};
        const float ah[3] = {1.625f, 3.75f, 2.875f};
        int a = 0; float best = -1.f;
        #pragma unroll
        for (int k = 0; k < 3; k++) {
            float inter = fminf(gtw, aw[k]) * fminf(gth, ah[k]);
            float uni   = gtw * gth + aw[k] * ah[k] - inter + 1e-9f;
            float r = inter / uni;
            if (r > best) { best = r; a = k; }
        }
        La[t] = a;
        Lc[t] = lc[b * NLAB + t];
    }
    __syncthreads();

    int cand = (pb % 108) * 4 + wid;          // [0, 432)
    int n = cand / 9, off = cand % 9;
    int gi = Lgi[n], gj = Lgj[n], a = La[n];
    int ii = clampi(gi + off / 3 - 1, 0, 79);
    int jj = clampi(gj + off % 3 - 1, 0, 79);

    // ownership: one ballot. lanes 0..8: clip-duplicate dedup; lanes 9..55:
    // later same-anchor label covering this cell overwrites us.
    bool viol = false;
    if (lane < 9) {
        if (lane < off) {
            int i2 = clampi(gi + lane / 3 - 1, 0, 79);
            int j2 = clampi(gj + lane % 3 - 1, 0, 79);
            viol = (i2 == ii) && (j2 == jj);
        }
    } else {
        int n2 = n + 1 + (lane - 9);
        if (n2 < NLAB && La[n2] == a) {
            int g2 = Lgi[n2], h2 = Lgj[n2];
            viol = ii >= max(g2 - 1, 0) && ii <= min(g2 + 1, 79) &&
                   jj >= max(h2 - 1, 0) && jj <= min(h2 + 1, 79);
        }
    }
    bool own = (__ballot(viol) == 0ull);

    float box = 0.f, cls = 0.f, xc = 0.f, npf = 0.f;
    if (own) {  // wave-uniform branch
        int cell = ((b * NA + a) * HW + jj) * HW + ii;
        const float* pc = p + (size_t)cell * D_;
        int c = Lc[n];

        float x = pc[5 + lane];
        float cs = softplusf(x) - ((lane == c) ? x : 0.f);
        if (lane < 16) {
            float x2 = pc[69 + lane];
            cs += softplusf(x2) - ((lane + 64 == c) ? x2 : 0.f);
        }
        #pragma unroll
        for (int o = 32; o; o >>= 1) cs += __shfl_xor(cs, o);

        if (lane == 0) {
            npf = 1.f;
            cls = cs;
            xc  = pc[4];

            float awv = (a == 0) ? 10.f : ((a == 1) ? 16.f : 33.f);
            float ahv = (a == 0) ? 13.f : ((a == 1) ? 30.f : 23.f);
            float p0 = pc[0], p1 = pc[1], p2 = pc[2], p3 = pc[3];
            float sx = 1.f / (1.f + expf(-p0));
            float sy = 1.f / (1.f + expf(-p1));
            float px = ((float)ii + sx) * 8.f;
            float py = ((float)jj + sy) * 8.f;
            float pw = expf(p2) * awv;
            float ph = expf(p3) * ahv;

            float gx = Lgx[n], gy = Lgy[n], gw = Lgw[n], gh = Lgh[n];

            float px1 = px - pw * 0.5f, px2 = px + pw * 0.5f;
            float py1 = py - ph * 0.5f, py2 = py + ph * 0.5f;
            float gx1 = gx - gw * 0.5f, gx2 = gx + gw * 0.5f;
            float gy1 = gy - gh * 0.5f, gy2 = gy + gh * 0.5f;

            float iw = fmaxf(fminf(px2, gx2) - fmaxf(px1, gx1), 0.f);
            float ih = fmaxf(fminf(py2, gy2) - fmaxf(py1, gy1), 0.f);
            float inter = iw * ih;
            float ap = fmaxf(px2 - px1, 0.f) * fmaxf(py2 - py1, 0.f);
            float ag = fmaxf(gx2 - gx1, 0.f) * fmaxf(gy2 - gy1, 0.f);
            float uni = ap + ag - inter + 1e-7f;
            float iou = inter / uni;

            float cw = fmaxf(fmaxf(px2, gx2) - fminf(px1, gx1), 0.f);
            float ch = fmaxf(fmaxf(py2, gy2) - fminf(py1, gy1), 0.f);
            float c2 = cw * cw + ch * ch + 1e-7f;
            float rho2 = (px - gx) * (px - gx) + (py - gy) * (py - gy);

            float dv = atanf(gw / (gh + 1e-7f)) - atanf(pw / (ph + 1e-7f));
            float v = 0.40528473456935108577f * dv * dv;   // 4/pi^2
            float alpha = v / (1.f - iou + v + 1e-7f);
            box = 1.f - (iou - rho2 / c2 - alpha * v);
        }
    }

    if (lane == 0) { r4[wid][0] = box; r4[wid][1] = cls; r4[wid][2] = xc; r4[wid][3] = npf; }
    __syncthreads();
    if (t == 0) {
        float4 o;
        o.x = r4[0][0] + r4[1][0] + r4[2][0] + r4[3][0];
        o.y = r4[0][1] + r4[1][1] + r4[2][1] + r4[3][1];
        o.z = r4[0][2] + r4[1][2] + r4[2][2] + r4[3][2];
        o.w = r4[0][3] + r4[1][3] + r4[2][3] + r4[3][3];
        ((float4*)ppart)[pb] = o;
    }
}

// ---------------------------------------------------------------------------
// k_fin: reduce 300 obj partials + 1728 pos float4 partials, compose scalar.
// ---------------------------------------------------------------------------
__global__ __launch_bounds__(256) void k_fin(const float* __restrict__ opart,
                                             const float* __restrict__ ppart,
                                             float* __restrict__ out) {
    int t = threadIdx.x, lane = t & 63, wid = t >> 6;
    float o = 0.f, box = 0.f, cls = 0.f, xc = 0.f, np = 0.f;
    if (t < OBJBLK) o = opart[t];
    #pragma unroll
    for (int k = 0; k < 7; k++) {
        int i = t + k * 256;
        if (i < POSBLK) {
            float4 v = ((const float4*)ppart)[i];
            box += v.x; cls += v.y; xc += v.z; np += v.w;
        }
    }
    #pragma unroll
    for (int s = 32; s; s >>= 1) {
        o   += __shfl_xor(o,   s);
        box += __shfl_xor(box, s);
        cls += __shfl_xor(cls, s);
        xc  += __shfl_xor(xc,  s);
        np  += __shfl_xor(np,  s);
    }
    __shared__ float r[4][5];
    if (lane == 0) { r[wid][0]=o; r[wid][1]=box; r[wid][2]=cls; r[wid][3]=xc; r[wid][4]=np; }
    __syncthreads();
    if (t == 0) {
        float O  = r[0][0] + r[1][0] + r[2][0] + r[3][0];
        float Bx = r[0][1] + r[1][1] + r[2][1] + r[3][1];
        float Cl = r[0][2] + r[1][2] + r[2][2] + r[3][2];
        float Xc = r[0][3] + r[1][3] + r[2][3] + r[3][3];
        float Np = r[0][4] + r[1][4] + r[2][4] + r[3][4];
        float npos = fmaxf(Np, 1.f);
        out[0] = 7.5f * Bx / npos
               + (O - Xc) / (float)NCELL
               + 0.5f * Cl / (npos * (float)NC);
    }
}

extern "C" void kernel_launch(void* const* d_in, const int* in_sizes, int n_in,
                              void* d_out, int out_size, void* d_ws, size_t ws_size,
                              hipStream_t stream) {
    const float* p  = (const float*)d_in[0];
    const float* lx = (const float*)d_in[1];
    const int*   lc = (const int*)d_in[2];
    float*       out = (float*)d_out;

    float* opart = (float*)d_ws;                          // 300 floats
    float* ppart = (float*)((char*)d_ws + 8192);          // 1728 float4

    k_main<<<NBLK_T, 256, 0, stream>>>(p, lx, lc, opart, ppart);
    k_fin<<<1, 256, 0, stream>>>(opart, ppart, out);
}